// Round 11
// baseline (414.457 us; speedup 1.0000x reference)
//
#include <hip/hip_runtime.h>
#include <hip/hip_bf16.h>

typedef __attribute__((ext_vector_type(8))) short short8;
typedef __attribute__((ext_vector_type(4))) float floatx4;

#define LN_EPS 1e-5f
// exp(score/8) = exp2(score * 0.125 * log2(e)); folded into Q at QKV epilogue
#define EXP2_SCALE 0.18033688011112042f

__device__ __forceinline__ float b2f(unsigned short u) {
    union { float f; unsigned int i; } x; x.i = ((unsigned int)u) << 16; return x.f;
}
__device__ __forceinline__ unsigned short f2b(float f) {
    union { float f; unsigned int i; } x; x.f = f;
    unsigned int r = x.i + 0x7fffu + ((x.i >> 16) & 1u);
    return (unsigned short)(r >> 16);
}
// packed f32x2 -> bf16x2 (RNE), single VALU op; lo = a, hi = b
__device__ __forceinline__ unsigned int cvtpk(float a, float b) {
    unsigned int r;
    asm("v_cvt_pk_bf16_f32 %0, %1, %2" : "=v"(r) : "v"(a), "v"(b));
    return r;
}

// async global->LDS, 16B/lane. LDS dest = wave-uniform base + lane*16 (per-lane global addr OK).
__device__ __forceinline__ void async16(const unsigned short* g, unsigned short* l) {
    __builtin_amdgcn_global_load_lds(
        (const __attribute__((address_space(1))) unsigned int*)g,
        (__attribute__((address_space(3))) unsigned int*)l, 16, 0, 0);
}

// ---------------- shared LN row routine (one block = one row of 1024) ----------------
// Vectorized: thread t owns contiguous cols [4t,4t+4) -> one ushort4/float4 load, uint2 store.
template<typename T>
__device__ __forceinline__ void ln_row(const T* __restrict__ xr, const float* __restrict__ g,
                                       const float* __restrict__ bb, unsigned short* __restrict__ outr,
                                       float* red)
{
    const int tid = threadIdx.x;
    float v[4];
    if constexpr (sizeof(T) == 4) {
        float4 t = *reinterpret_cast<const float4*>(xr + tid * 4);
        v[0] = t.x; v[1] = t.y; v[2] = t.z; v[3] = t.w;
    } else {
        ushort4 t = *reinterpret_cast<const ushort4*>(xr + tid * 4);
        v[0] = b2f(t.x); v[1] = b2f(t.y); v[2] = b2f(t.z); v[3] = b2f(t.w);
    }
    float s  = v[0] + v[1] + v[2] + v[3];
    float sq = v[0]*v[0] + v[1]*v[1] + v[2]*v[2] + v[3]*v[3];
#pragma unroll
    for (int o = 32; o >= 1; o >>= 1) {
        s  += __shfl_xor(s,  o, 64);
        sq += __shfl_xor(sq, o, 64);
    }
    const int wave = tid >> 6, lane = tid & 63;
    if (lane == 0) { red[wave] = s; red[4 + wave] = sq; }
    __syncthreads();
    s  = red[0] + red[1] + red[2] + red[3];
    sq = red[4] + red[5] + red[6] + red[7];
    const float mu  = s * (1.0f / 1024.0f);
    const float var = sq * (1.0f / 1024.0f) - mu * mu;
    const float rs  = rsqrtf(var + LN_EPS);
    float4 g4 = *reinterpret_cast<const float4*>(g  + tid * 4);
    float4 b4 = *reinterpret_cast<const float4*>(bb + tid * 4);
    float r0 = (v[0] - mu) * rs * g4.x + b4.x;
    float r1 = (v[1] - mu) * rs * g4.y + b4.y;
    float r2 = (v[2] - mu) * rs * g4.z + b4.z;
    float r3 = (v[3] - mu) * rs * g4.w + b4.w;
    *reinterpret_cast<uint2*>(outr + tid * 4) = make_uint2(cvtpk(r0, r1), cvtpk(r2, r3));
}

// ---------------- prep: blocks [0,5120) cvt weights; [5120,13312) LN1 rows ----------------
__global__ __launch_bounds__(256)
void prep_kernel(const float* __restrict__ Wq, const float* __restrict__ Wk,
                 const float* __restrict__ Wv, const float* __restrict__ Wo,
                 const float* __restrict__ W1, const float* __restrict__ W2,
                 unsigned short* __restrict__ wdst,
                 const float* __restrict__ x, const float* __restrict__ ln1g,
                 const float* __restrict__ ln1b, unsigned short* __restrict__ xn)
{
    __shared__ float red[8];
    if (blockIdx.x < 5120) {
        const size_t i = (size_t)(blockIdx.x * 256 + threadIdx.x) * 8;
        const float* src; size_t off;
        if (i < 4194304) {
            int w = (int)(i >> 20);
            src = (w == 0) ? Wq : (w == 1) ? Wk : (w == 2) ? Wv : Wo;
            off = i & 1048575;
        } else if (i < 8388608) { src = W1; off = i - 4194304; }
        else                    { src = W2; off = i - 8388608; }
        float4 a = *reinterpret_cast<const float4*>(src + off);
        float4 b = *reinterpret_cast<const float4*>(src + off + 4);
        short8 r;
        r[0] = (short)f2b(a.x); r[1] = (short)f2b(a.y);
        r[2] = (short)f2b(a.z); r[3] = (short)f2b(a.w);
        r[4] = (short)f2b(b.x); r[5] = (short)f2b(b.y);
        r[6] = (short)f2b(b.z); r[7] = (short)f2b(b.w);
        *reinterpret_cast<short8*>(wdst + i) = r;
    } else {
        const int row = blockIdx.x - 5120;
        ln_row<float>(x + (size_t)row * 1024, ln1g, ln1b, xn + (size_t)row * 1024, red);
    }
}

// ---------------- standalone LN (for LN2, bf16 in) ----------------
__global__ __launch_bounds__(256)
void ln_kernel(const unsigned short* __restrict__ x, const float* __restrict__ g,
               const float* __restrict__ bb, unsigned short* __restrict__ out)
{
    __shared__ float red[8];
    const int row = blockIdx.x;
    ln_row<unsigned short>(x + (size_t)row * 1024, g, bb, out + (size_t)row * 1024, red);
}

// ================= GEMM core: 16x16x32 MFMA, BK=64, XOR-swizzled [128][64] LDS ==============
// 2-resident/CU regime -> overlapped single-buffer schedule (3x verified: R9 w1, R10 nt pair):
// frags->regs, lgkm(0)+barrier, DMA t+1 into SAME buffer under the MFMA cluster, vmcnt(0)
// (a full cluster old = free) + barrier.
// EPI 1: bf16 out = acc + bias + fp32 residual   (Wo -> x1b)
// EPI 2: fp32 out = acc + bias + bf16 residual   (W2 -> final out)
template<int EPI>
__global__ __launch_bounds__(256, 2)
void gemm_nt(const unsigned short* __restrict__ A, const unsigned short* __restrict__ B,
             const float* __restrict__ bias, const void* __restrict__ res,
             void* __restrict__ C, int M, int N, int K)
{
    __shared__ unsigned short As[128 * 64];
    __shared__ unsigned short Bs[128 * 64];
    const int m0 = blockIdx.y * 128, n0 = blockIdx.x * 128;
    const int tid = threadIdx.x, wave = tid >> 6, lane = tid & 63;
    const int wm = (wave >> 1) * 64, wn = (wave & 1) * 64;
    const int lrow = lane & 15, quad = lane >> 4;
    const int srow = wave * 32 + (lane >> 3);
    const int scol = (((lane & 7) ^ ((lane >> 3) & 7)) << 3);
    const int ca0 = (quad ^ (lrow & 7)) << 3;
    const int ca1 = ((quad + 4) ^ (lrow & 7)) << 3;

    floatx4 acc[4][4] = {};
    const unsigned short* gA = A + (size_t)(m0 + srow) * K + scol;
    const unsigned short* gB = B + (size_t)(n0 + srow) * K + scol;
    unsigned short* lA = &As[(wave * 32) * 64];
    unsigned short* lB = &Bs[(wave * 32) * 64];

    auto stage = [&](int kk) {
#pragma unroll
        for (int r = 0; r < 4; r++) {
            async16(gA + kk + (size_t)(r * 8) * K, lA + r * 8 * 64);
            async16(gB + kk + (size_t)(r * 8) * K, lB + r * 8 * 64);
        }
    };

    stage(0);
    __syncthreads();                                  // tile 0 resident

    for (int k0 = 0; k0 < K; k0 += 64) {
        // hoist ALL fragments of tile t into registers
        short8 af[4][2], bf[4][2];
#pragma unroll
        for (int ks = 0; ks < 2; ks++) {
            const int ca = ks ? ca1 : ca0;
#pragma unroll
            for (int i = 0; i < 4; i++)
                af[i][ks] = *reinterpret_cast<const short8*>(&As[(wm + i * 16 + lrow) * 64 + ca]);
#pragma unroll
            for (int j = 0; j < 4; j++)
                bf[j][ks] = *reinterpret_cast<const short8*>(&Bs[(wn + j * 16 + lrow) * 64 + ca]);
        }
        __asm__ volatile("s_waitcnt lgkmcnt(0)" ::: "memory");  // frags landed in regs
        __builtin_amdgcn_sched_barrier(0);                      // rule #18 fence
        __builtin_amdgcn_s_barrier();                           // all waves done reading LDS

        if (k0 + 64 < K) stage(k0 + 64);                        // DMA t+1 under the MFMA cluster

        __builtin_amdgcn_s_setprio(1);
#pragma unroll
        for (int ks = 0; ks < 2; ks++)
#pragma unroll
            for (int i = 0; i < 4; i++)
#pragma unroll
                for (int j = 0; j < 4; j++)
                    acc[i][j] = __builtin_amdgcn_mfma_f32_16x16x32_bf16(af[i][ks], bf[j][ks], acc[i][j], 0, 0, 0);
        __builtin_amdgcn_s_setprio(0);

        __asm__ volatile("s_waitcnt vmcnt(0)" ::: "memory");    // t+1's DMA done (a cluster old)
        __builtin_amdgcn_s_barrier();
        __builtin_amdgcn_sched_barrier(0);
    }

#pragma unroll
    for (int i = 0; i < 4; i++) {
        int rb = m0 + wm + i * 16 + quad * 4;
#pragma unroll
        for (int j = 0; j < 4; j++) {
            int col = n0 + wn + j * 16 + lrow;
            float bv = bias[col];
#pragma unroll
            for (int r = 0; r < 4; r++) {
                size_t idx = (size_t)(rb + r) * N + col;
                float v = acc[i][j][r] + bv;
                if (EPI == 1) {
                    v += ((const float*)res)[idx];
                    ((unsigned short*)C)[idx] = f2b(v);
                } else {
                    v += b2f(((const unsigned short*)res)[idx]);
                    ((float*)C)[idx] = v;
                }
            }
        }
    }
}

// ---------------- fused QKV (BK=64 swizzled); Q pre-scaled; V -> per-head transposed Vt ------
// Vt keys PRE-PERMUTED within each 32-key window by pi^-1 so attn's PV consumes P directly
// from registers: pi(quad*8+i) = (i>>2)*16 + quad*4 + (i&3)  [A-slot -> key], bijective on [0,32).
// Moved into the verified 2-resident overlap regime: launch_bounds(256,2), 1536 blocks =
// exactly 3 rounds of 512 (zero tail); VGPR headroom for hoisted frags (acc64+frags64 < 256).
__global__ __launch_bounds__(256, 2)
void gemm_qkv(const unsigned short* __restrict__ A, const unsigned short* __restrict__ Wqkv,
              const float* __restrict__ bq, const float* __restrict__ bk, const float* __restrict__ bv,
              unsigned short* __restrict__ QK, unsigned short* __restrict__ Vt)
{
    __shared__ unsigned short As[128 * 64];
    __shared__ unsigned short Bs[128 * 64];
    const int part = blockIdx.x >> 3;            // 0=Q 1=K 2=V
    const int m0 = blockIdx.y * 128, n0 = (blockIdx.x & 7) * 128;
    const int tid = threadIdx.x, wave = tid >> 6, lane = tid & 63;
    const int wm = (wave >> 1) * 64, wn = (wave & 1) * 64;
    const int lrow = lane & 15, quad = lane >> 4;
    const int srow = wave * 32 + (lane >> 3);
    const int scol = (((lane & 7) ^ ((lane >> 3) & 7)) << 3);
    const int ca0 = (quad ^ (lrow & 7)) << 3;
    const int ca1 = ((quad + 4) ^ (lrow & 7)) << 3;
    const unsigned short* B = Wqkv + (size_t)part * 1048576;
    const float* bias = (part == 0) ? bq : (part == 1) ? bk : bv;

    floatx4 acc[4][4] = {};
    const unsigned short* gA = A + (size_t)(m0 + srow) * 1024 + scol;
    const unsigned short* gB = B + (size_t)(n0 + srow) * 1024 + scol;
    unsigned short* lA = &As[(wave * 32) * 64];
    unsigned short* lB = &Bs[(wave * 32) * 64];

    auto stage = [&](int kk) {
#pragma unroll
        for (int r = 0; r < 4; r++) {
            async16(gA + kk + (size_t)(r * 8) * 1024, lA + r * 8 * 64);
            async16(gB + kk + (size_t)(r * 8) * 1024, lB + r * 8 * 64);
        }
    };

    stage(0);
    __syncthreads();                                  // tile 0 resident

    for (int k0 = 0; k0 < 1024; k0 += 64) {
        // hoist ALL fragments of tile t into registers
        short8 af[4][2], bf[4][2];
#pragma unroll
        for (int ks = 0; ks < 2; ks++) {
            const int ca = ks ? ca1 : ca0;
#pragma unroll
            for (int i = 0; i < 4; i++)
                af[i][ks] = *reinterpret_cast<const short8*>(&As[(wm + i * 16 + lrow) * 64 + ca]);
#pragma unroll
            for (int j = 0; j < 4; j++)
                bf[j][ks] = *reinterpret_cast<const short8*>(&Bs[(wn + j * 16 + lrow) * 64 + ca]);
        }
        __asm__ volatile("s_waitcnt lgkmcnt(0)" ::: "memory");  // frags landed in regs
        __builtin_amdgcn_sched_barrier(0);                      // rule #18 fence
        __builtin_amdgcn_s_barrier();                           // all waves done reading LDS

        if (k0 < 960) stage(k0 + 64);                           // DMA t+1 under the MFMA cluster

        __builtin_amdgcn_s_setprio(1);
#pragma unroll
        for (int ks = 0; ks < 2; ks++)
#pragma unroll
            for (int i = 0; i < 4; i++)
#pragma unroll
                for (int j = 0; j < 4; j++)
                    acc[i][j] = __builtin_amdgcn_mfma_f32_16x16x32_bf16(af[i][ks], bf[j][ks], acc[i][j], 0, 0, 0);
        __builtin_amdgcn_s_setprio(0);

        __asm__ volatile("s_waitcnt vmcnt(0)" ::: "memory");    // t+1's DMA done (a cluster old)
        __builtin_amdgcn_s_barrier();
        __builtin_amdgcn_sched_barrier(0);
    }

#pragma unroll
    for (int i = 0; i < 4; i++) {
        int rb = m0 + wm + i * 16 + quad * 4;
#pragma unroll
        for (int j = 0; j < 4; j++) {
            int col = n0 + wn + j * 16 + lrow;
            float bv2 = bias[col];
            if (part == 0) {
#pragma unroll
                for (int r = 0; r < 4; r++)
                    QK[(size_t)(rb + r) * 1024 + col] = f2b((acc[i][j][r] + bv2) * EXP2_SCALE);
            } else if (part == 1) {
                unsigned short* dst = QK + 8388608;
#pragma unroll
                for (int r = 0; r < 4; r++)
                    dst[(size_t)(rb + r) * 1024 + col] = f2b(acc[i][j][r] + bv2);
            } else {
                int b = rb >> 11, spos = rb & 2047;
                // pi^-1 on the 32-key window: key k -> slot ((k>>2)&3)*8 + (k>>4)*4 + (k&3);
                // rb is 4-aligned so the 4 r-values stay contiguous.
                int local = spos & 31;
                int sposP = (spos & ~31) | (((local >> 2) & 3) * 8 + ((local >> 4) << 2));
                int h = col >> 6, d = col & 63;
                unsigned short* dst = Vt + (((size_t)(b * 16 + h) * 64 + d) << 11) + sposP;
                unsigned int u01 = cvtpk(acc[i][j][0] + bv2, acc[i][j][1] + bv2);
                unsigned int u23 = cvtpk(acc[i][j][2] + bv2, acc[i][j][3] + bv2);
                *reinterpret_cast<uint2*>(dst) = make_uint2(u01, u23);
            }
        }
    }
}

// ---------------- Fused W1 + ReGLU (BK=64 swizzled), overlapped single-buffer staging -------
// R9-verified: per tile: hoist all 24 frags to regs -> lgkm(0)+barrier (LDS free) -> DMA tile
// t+1 into SAME buffer -> 64-MFMA cluster overlaps DMA -> vmcnt(0) (a cluster old) + barrier.
__global__ __launch_bounds__(256, 2)
void gemm_w1_reglu(const unsigned short* __restrict__ A, const unsigned short* __restrict__ B,
                   const float* __restrict__ bias, unsigned short* __restrict__ G)
{
    __shared__ unsigned short As[128 * 64];
    __shared__ unsigned short B0s[128 * 64];
    __shared__ unsigned short B1s[128 * 64];
    const int m0 = blockIdx.y * 128, n0 = blockIdx.x * 128;  // n0 in [0,2048)
    const int tid = threadIdx.x, wave = tid >> 6, lane = tid & 63;
    const int wm = (wave >> 1) * 64, wn = (wave & 1) * 64;
    const int lrow = lane & 15, quad = lane >> 4;
    const int srow = wave * 32 + (lane >> 3);
    const int scol = (((lane & 7) ^ ((lane >> 3) & 7)) << 3);
    const int ca0 = (quad ^ (lrow & 7)) << 3;
    const int ca1 = ((quad + 4) ^ (lrow & 7)) << 3;

    floatx4 acca[4][4] = {};
    floatx4 accb[4][4] = {};
    const unsigned short* gA  = A + (size_t)(m0 + srow) * 1024 + scol;
    const unsigned short* gB0 = B + (size_t)(n0 + srow) * 1024 + scol;
    const unsigned short* gB1 = B + (size_t)(2048 + n0 + srow) * 1024 + scol;
    unsigned short* lA  = &As [(wave * 32) * 64];
    unsigned short* lB0 = &B0s[(wave * 32) * 64];
    unsigned short* lB1 = &B1s[(wave * 32) * 64];

    auto stage = [&](int kk) {
#pragma unroll
        for (int r = 0; r < 4; r++) {
            async16(gA  + kk + (size_t)(r * 8) * 1024, lA  + r * 8 * 64);
            async16(gB0 + kk + (size_t)(r * 8) * 1024, lB0 + r * 8 * 64);
            async16(gB1 + kk + (size_t)(r * 8) * 1024, lB1 + r * 8 * 64);
        }
    };

    stage(0);
    __syncthreads();                                  // tile 0 resident

    for (int k0 = 0; k0 < 1024; k0 += 64) {
        // hoist ALL fragments of tile t into registers
        short8 af[4][2], b0f[4][2], b1f[4][2];
#pragma unroll
        for (int ks = 0; ks < 2; ks++) {
            const int ca = ks ? ca1 : ca0;
#pragma unroll
            for (int i = 0; i < 4; i++)
                af[i][ks] = *reinterpret_cast<const short8*>(&As[(wm + i * 16 + lrow) * 64 + ca]);
#pragma unroll
            for (int j = 0; j < 4; j++) {
                b0f[j][ks] = *reinterpret_cast<const short8*>(&B0s[(wn + j * 16 + lrow) * 64 + ca]);
                b1f[j][ks] = *reinterpret_cast<const short8*>(&B1s[(wn + j * 16 + lrow) * 64 + ca]);
            }
        }
        __asm__ volatile("s_waitcnt lgkmcnt(0)" ::: "memory");  // frags landed in regs
        __builtin_amdgcn_sched_barrier(0);                      // rule #18 fence
        __builtin_amdgcn_s_barrier();                           // all waves done reading LDS

        if (k0 < 960) stage(k0 + 64);                           // DMA t+1 under the MFMA cluster

        __builtin_amdgcn_s_setprio(1);
#pragma unroll
        for (int ks = 0; ks < 2; ks++)
#pragma unroll
            for (int i = 0; i < 4; i++)
#pragma unroll
                for (int j = 0; j < 4; j++) {
                    acca[i][j] = __builtin_amdgcn_mfma_f32_16x16x32_bf16(af[i][ks], b0f[j][ks], acca[i][j], 0, 0, 0);
                    accb[i][j] = __builtin_amdgcn_mfma_f32_16x16x32_bf16(af[i][ks], b1f[j][ks], accb[i][j], 0, 0, 0);
                }
        __builtin_amdgcn_s_setprio(0);

        __asm__ volatile("s_waitcnt vmcnt(0)" ::: "memory");    // t+1's DMA done (a cluster old)
        __builtin_amdgcn_s_barrier();
        __builtin_amdgcn_sched_barrier(0);
    }

#pragma unroll
    for (int i = 0; i < 4; i++) {
        int rb = m0 + wm + i * 16 + quad * 4;
#pragma unroll
        for (int j = 0; j < 4; j++) {
            int col = n0 + wn + j * 16 + lrow;
            float ba = bias[col], bb2 = bias[2048 + col];
#pragma unroll
            for (int r = 0; r < 4; r++) {
                float va = acca[i][j][r] + ba;
                float vb = accb[i][j][r] + bb2;
                G[(size_t)(rb + r) * 2048 + col] = f2b(fmaxf(va, 0.0f) * vb);
            }
        }
    }
}

// ---------------- Flash attention: register-P + K/V dbuf, occupancy 4, XCD-swizzled ----------
// R8-verified (77.6 us, bank conflicts = 0): P never touches LDS (Vt pre-permuted by pi so the
// S^T C-layout registers ARE the PV A-operand after cvtpk); K/V double-buffered with counted
// vmcnt(4) + raw barriers at 4 blocks/CU; per-XCD K/V = 4MB = one L2.
__global__ __launch_bounds__(256, 4)
void attn_kernel(const unsigned short* __restrict__ Qm, const unsigned short* __restrict__ Km,
                 const unsigned short* __restrict__ Vt, unsigned short* __restrict__ ctx)
{
    __shared__ unsigned short Ks[2][64 * 64];   // [buf][key][d], chunk-swizzled
    __shared__ unsigned short Vs[2][64 * 64];   // [buf][d][key(pi-permuted)], chunk-swizzled

    const int tid = threadIdx.x, wave = tid >> 6, lane = tid & 63;
    const int lrow = lane & 15, quad = lane >> 4;
    const int id = blockIdx.x + (blockIdx.y << 4);          // grid (16,64), 1024 blocks
    const int qb = id >> 6;                                 // [0,16)
    const int bh = ((id & 7) << 3) + ((id >> 3) & 7);       // [0,64): XCD x -> heads [8x,8x+8)
    const size_t base  = (size_t)(bh >> 4) * 2048 * 1024 + (size_t)(bh & 15) * 64;
    const size_t vbase = (size_t)bh * 131072;   // Vt head base [d][2048]
    const int q0 = qb * 128 + wave * 32;
    const int g_sub = (lane >> 3);
    const int g_col = (((lane & 7) ^ (g_sub & 7)) << 3);
    const int ca0 = (quad ^ (lrow & 7)) << 3;
    const int ca1 = ((quad + 4) ^ (lrow & 7)) << 3;

    short8 qf[2][2];
#pragma unroll
    for (int m = 0; m < 2; m++) {
        const unsigned short* qp = Qm + base + (size_t)(q0 + m * 16 + lrow) * 1024 + quad * 8;
        qf[m][0] = *reinterpret_cast<const short8*>(qp);
        qf[m][1] = *reinterpret_cast<const short8*>(qp + 32);
    }
    __asm__ volatile("s_waitcnt vmcnt(0)" ::: "memory");  // Q drained: steady-state vmcnt = DMA only

    floatx4 o[2][4] = {};
    float li[2] = {0.f, 0.f};
    const floatx4 fzero = {0.f, 0.f, 0.f, 0.f};

    auto stage = [&](int buf, int k0) {
#pragma unroll
        for (int r = 0; r < 2; r++) {
            int krow = wave * 16 + r * 8 + g_sub;
            async16(Km + base + (size_t)(k0 + krow) * 1024 + g_col, &Ks[buf][(wave * 16 + r * 8) * 64]);
            async16(Vt + vbase + (size_t)krow * 2048 + k0 + g_col,  &Vs[buf][(wave * 16 + r * 8) * 64]);
        }
    };

    auto compute = [&](int buf) {
        // S^T = K Q^T (Q pre-scaled by 0.125*log2e)
        short8 kf0[4], kf1[4];
#pragma unroll
        for (int j = 0; j < 4; j++) {
            kf0[j] = *reinterpret_cast<const short8*>(&Ks[buf][(j * 16 + lrow) * 64 + ca0]);
            kf1[j] = *reinterpret_cast<const short8*>(&Ks[buf][(j * 16 + lrow) * 64 + ca1]);
        }
        floatx4 s4t[2][4];
        __builtin_amdgcn_s_setprio(1);
#pragma unroll
        for (int m = 0; m < 2; m++)
#pragma unroll
            for (int j = 0; j < 4; j++) {
                s4t[m][j] = __builtin_amdgcn_mfma_f32_16x16x32_bf16(kf0[j], qf[m][0], fzero, 0, 0, 0);
                s4t[m][j] = __builtin_amdgcn_mfma_f32_16x16x32_bf16(kf1[j], qf[m][1], s4t[m][j], 0, 0, 0);
            }
        __builtin_amdgcn_s_setprio(0);

        // p = exp2(s) packed straight into PV A-fragments (register order (j,r) == pi slot order)
        short8 pfs[2][2];
#pragma unroll
        for (int m = 0; m < 2; m++) {
            float acc = 0.f;
            unsigned int dw[8];
#pragma unroll
            for (int j = 0; j < 4; j++) {
                float p0 = __builtin_amdgcn_exp2f(s4t[m][j][0]);
                float p1 = __builtin_amdgcn_exp2f(s4t[m][j][1]);
                float p2 = __builtin_amdgcn_exp2f(s4t[m][j][2]);
                float p3 = __builtin_amdgcn_exp2f(s4t[m][j][3]);
                acc += (p0 + p1) + (p2 + p3);
                dw[2 * j]     = cvtpk(p0, p1);
                dw[2 * j + 1] = cvtpk(p2, p3);
            }
            li[m] += acc;
            pfs[m][0] = *reinterpret_cast<const short8*>(&dw[0]);
            pfs[m][1] = *reinterpret_cast<const short8*>(&dw[4]);
        }

        // O += P V (V keys pre-permuted to match)
#pragma unroll
        for (int jj = 0; jj < 4; jj++) {
            short8 vf0 = *reinterpret_cast<const short8*>(&Vs[buf][(jj * 16 + lrow) * 64 + ca0]);
            short8 vf1 = *reinterpret_cast<const short8*>(&Vs[buf][(jj * 16 + lrow) * 64 + ca1]);
            __builtin_amdgcn_s_setprio(1);
#pragma unroll
            for (int m = 0; m < 2; m++) {
                o[m][jj] = __builtin_amdgcn_mfma_f32_16x16x32_bf16(pfs[m][0], vf0, o[m][jj], 0, 0, 0);
                o[m][jj] = __builtin_amdgcn_mfma_f32_16x16x32_bf16(pfs[m][1], vf1, o[m][jj], 0, 0, 0);
            }
            __builtin_amdgcn_s_setprio(0);
        }
    };

    stage(0, 0);
    for (int t = 0; t < 31; t++) {
        stage((t + 1) & 1, (t + 1) << 6);                    // prefetch next tile into other buf
        __asm__ volatile("s_waitcnt vmcnt(4)" ::: "memory"); // tile t's 4 DMA done; t+1's in flight
        __builtin_amdgcn_s_barrier();
        __builtin_amdgcn_sched_barrier(0);                   // no LDS reads above the barrier
        compute(t & 1);
        __builtin_amdgcn_sched_barrier(0);                   // no LDS ops below the barrier
        __builtin_amdgcn_s_barrier();                        // buf(t&1) free for overwrite next iter
    }
    __asm__ volatile("s_waitcnt vmcnt(0)" ::: "memory");     // drain tile 31
    __builtin_amdgcn_s_barrier();
    __builtin_amdgcn_sched_barrier(0);
    compute(1);

    // epilogue: row-sum across quads; per-row inv via shuffle
#pragma unroll
    for (int m = 0; m < 2; m++) {
        float l = li[m];
        l += __shfl_xor(l, 16, 64);
        l += __shfl_xor(l, 32, 64);
        float inv = 1.0f / l;
#pragma unroll
        for (int r = 0; r < 4; r++) {
            float invr = __shfl(inv, quad * 4 + r, 64);
            int srow = q0 + m * 16 + quad * 4 + r;
#pragma unroll
            for (int jj = 0; jj < 4; jj++)
                ctx[base + (size_t)srow * 1024 + jj * 16 + lrow] = f2b(o[m][jj][r] * invr);
        }
    }
}

extern "C" void kernel_launch(void* const* d_in, const int* in_sizes, int n_in,
                              void* d_out, int out_size, void* d_ws, size_t ws_size,
                              hipStream_t stream) {
    const float* x    = (const float*)d_in[0];
    const float* Wq   = (const float*)d_in[1];
    const float* bq   = (const float*)d_in[2];
    const float* Wk   = (const float*)d_in[3];
    const float* bk   = (const float*)d_in[4];
    const float* Wv   = (const float*)d_in[5];
    const float* bv   = (const float*)d_in[6];
    const float* Wo   = (const float*)d_in[7];
    const float* bo   = (const float*)d_in[8];
    const float* ln1g = (const float*)d_in[9];
    const float* ln1b = (const float*)d_in[10];
    const float* ln2g = (const float*)d_in[11];
    const float* ln2b = (const float*)d_in[12];
    const float* W1   = (const float*)d_in[13];
    const float* b1   = (const float*)d_in[14];
    const float* W2   = (const float*)d_in[15];
    const float* b2   = (const float*)d_in[16];
    float* out = (float*)d_out;

    char* ws = (char*)d_ws;
    // Workspace (100 MB peak):
    // [0,20MB)   bf16 weights flat: wq wk wv wo w1 w2
    // [20,36MB)  xn -> ctx -> xn2 (bf16 8192x1024)
    // [36,52MB)  Q   -> x1b (bf16 residual after attention)
    // [52,68MB)  K
    // [68,84MB)  Vt (pi-permuted keys)  }  g (bf16 8192x2048) overlays [68,100)
    unsigned short* wflat = (unsigned short*)ws;
    unsigned short* wqb = wflat;
    unsigned short* wob = wflat + 3145728;
    unsigned short* w1b = wflat + 4194304;
    unsigned short* w2b = wflat + 8388608;
    unsigned short* xn  = (unsigned short*)(ws + 20971520);
    unsigned short* Qm  = (unsigned short*)(ws + 37748736);
    unsigned short* x1b = (unsigned short*)(ws + 37748736);
    unsigned short* Vt  = (unsigned short*)(ws + 71303168);
    unsigned short* g   = (unsigned short*)(ws + 71303168);

    dim3 blk(256);
    // fused weight-cvt + LN1
    prep_kernel<<<13312, blk, 0, stream>>>(Wq, Wk, Wv, Wo, W1, W2, wflat, x, ln1g, ln1b, xn);
    gemm_qkv<<<dim3(24, 64), blk, 0, stream>>>(xn, wqb, bq, bk, bv, Qm, Vt);
    attn_kernel<<<dim3(16, 64), blk, 0, stream>>>(Qm, Qm + 8388608, Vt, xn);
    // Wo + residual(x fp32) -> x1b (bf16, overwrites Q region)
    gemm_nt<1><<<dim3(8, 64), blk, 0, stream>>>(xn, wob, bo, x, x1b, 8192, 1024, 1024);
    ln_kernel<<<8192, blk, 0, stream>>>(x1b, ln2g, ln2b, xn);
    gemm_w1_reglu<<<dim3(16, 64), blk, 0, stream>>>(xn, w1b, b1, g);
    // W2 + residual(x1b bf16) -> out fp32
    gemm_nt<2><<<dim3(8, 64), blk, 0, stream>>>(g, w2b, b2, x1b, out, 8192, 1024, 2048);
}

// Round 12
// 398.843 us; speedup vs baseline: 1.0392x; 1.0392x over previous
//
#include <hip/hip_runtime.h>
#include <hip/hip_bf16.h>

typedef __attribute__((ext_vector_type(8))) short short8;
typedef __attribute__((ext_vector_type(4))) float floatx4;

#define LN_EPS 1e-5f
// exp(score/8) = exp2(score * 0.125 * log2(e)); folded into Q at QKV epilogue
#define EXP2_SCALE 0.18033688011112042f

__device__ __forceinline__ float b2f(unsigned short u) {
    union { float f; unsigned int i; } x; x.i = ((unsigned int)u) << 16; return x.f;
}
__device__ __forceinline__ unsigned short f2b(float f) {
    union { float f; unsigned int i; } x; x.f = f;
    unsigned int r = x.i + 0x7fffu + ((x.i >> 16) & 1u);
    return (unsigned short)(r >> 16);
}
// packed f32x2 -> bf16x2 (RNE), single VALU op; lo = a, hi = b
__device__ __forceinline__ unsigned int cvtpk(float a, float b) {
    unsigned int r;
    asm("v_cvt_pk_bf16_f32 %0, %1, %2" : "=v"(r) : "v"(a), "v"(b));
    return r;
}

// async global->LDS, 16B/lane. LDS dest = wave-uniform base + lane*16 (per-lane global addr OK).
__device__ __forceinline__ void async16(const unsigned short* g, unsigned short* l) {
    __builtin_amdgcn_global_load_lds(
        (const __attribute__((address_space(1))) unsigned int*)g,
        (__attribute__((address_space(3))) unsigned int*)l, 16, 0, 0);
}

// ---------------- shared LN row routine (one block = one row of 1024) ----------------
// Vectorized: thread t owns contiguous cols [4t,4t+4) -> one ushort4/float4 load, uint2 store.
template<typename T>
__device__ __forceinline__ void ln_row(const T* __restrict__ xr, const float* __restrict__ g,
                                       const float* __restrict__ bb, unsigned short* __restrict__ outr,
                                       float* red)
{
    const int tid = threadIdx.x;
    float v[4];
    if constexpr (sizeof(T) == 4) {
        float4 t = *reinterpret_cast<const float4*>(xr + tid * 4);
        v[0] = t.x; v[1] = t.y; v[2] = t.z; v[3] = t.w;
    } else {
        ushort4 t = *reinterpret_cast<const ushort4*>(xr + tid * 4);
        v[0] = b2f(t.x); v[1] = b2f(t.y); v[2] = b2f(t.z); v[3] = b2f(t.w);
    }
    float s  = v[0] + v[1] + v[2] + v[3];
    float sq = v[0]*v[0] + v[1]*v[1] + v[2]*v[2] + v[3]*v[3];
#pragma unroll
    for (int o = 32; o >= 1; o >>= 1) {
        s  += __shfl_xor(s,  o, 64);
        sq += __shfl_xor(sq, o, 64);
    }
    const int wave = tid >> 6, lane = tid & 63;
    if (lane == 0) { red[wave] = s; red[4 + wave] = sq; }
    __syncthreads();
    s  = red[0] + red[1] + red[2] + red[3];
    sq = red[4] + red[5] + red[6] + red[7];
    const float mu  = s * (1.0f / 1024.0f);
    const float var = sq * (1.0f / 1024.0f) - mu * mu;
    const float rs  = rsqrtf(var + LN_EPS);
    float4 g4 = *reinterpret_cast<const float4*>(g  + tid * 4);
    float4 b4 = *reinterpret_cast<const float4*>(bb + tid * 4);
    float r0 = (v[0] - mu) * rs * g4.x + b4.x;
    float r1 = (v[1] - mu) * rs * g4.y + b4.y;
    float r2 = (v[2] - mu) * rs * g4.z + b4.z;
    float r3 = (v[3] - mu) * rs * g4.w + b4.w;
    *reinterpret_cast<uint2*>(outr + tid * 4) = make_uint2(cvtpk(r0, r1), cvtpk(r2, r3));
}

// ---------------- prep: blocks [0,5120) cvt weights; [5120,13312) LN1 rows ----------------
__global__ __launch_bounds__(256)
void prep_kernel(const float* __restrict__ Wq, const float* __restrict__ Wk,
                 const float* __restrict__ Wv, const float* __restrict__ Wo,
                 const float* __restrict__ W1, const float* __restrict__ W2,
                 unsigned short* __restrict__ wdst,
                 const float* __restrict__ x, const float* __restrict__ ln1g,
                 const float* __restrict__ ln1b, unsigned short* __restrict__ xn)
{
    __shared__ float red[8];
    if (blockIdx.x < 5120) {
        const size_t i = (size_t)(blockIdx.x * 256 + threadIdx.x) * 8;
        const float* src; size_t off;
        if (i < 4194304) {
            int w = (int)(i >> 20);
            src = (w == 0) ? Wq : (w == 1) ? Wk : (w == 2) ? Wv : Wo;
            off = i & 1048575;
        } else if (i < 8388608) { src = W1; off = i - 4194304; }
        else                    { src = W2; off = i - 8388608; }
        float4 a = *reinterpret_cast<const float4*>(src + off);
        float4 b = *reinterpret_cast<const float4*>(src + off + 4);
        short8 r;
        r[0] = (short)f2b(a.x); r[1] = (short)f2b(a.y);
        r[2] = (short)f2b(a.z); r[3] = (short)f2b(a.w);
        r[4] = (short)f2b(b.x); r[5] = (short)f2b(b.y);
        r[6] = (short)f2b(b.z); r[7] = (short)f2b(b.w);
        *reinterpret_cast<short8*>(wdst + i) = r;
    } else {
        const int row = blockIdx.x - 5120;
        ln_row<float>(x + (size_t)row * 1024, ln1g, ln1b, xn + (size_t)row * 1024, red);
    }
}

// ---------------- standalone LN (for LN2, bf16 in) ----------------
__global__ __launch_bounds__(256)
void ln_kernel(const unsigned short* __restrict__ x, const float* __restrict__ g,
               const float* __restrict__ bb, unsigned short* __restrict__ out)
{
    __shared__ float red[8];
    const int row = blockIdx.x;
    ln_row<unsigned short>(x + (size_t)row * 1024, g, bb, out + (size_t)row * 1024, red);
}

// ================= GEMM core: 16x16x32 MFMA, BK=64, XOR-swizzled [128][64] LDS ==============
// 2-resident/CU (grid-limited) -> overlapped single-buffer schedule (verified R9 w1, R10 nt):
// frags->regs, lgkm(0)+barrier, DMA t+1 into SAME buffer under the MFMA cluster, vmcnt(0)
// (a full cluster old = free) + barrier. NOTE (R11): do NOT cap occupancy to enable this —
// trading 3-resident for overlap measured -11us on qkv.
// EPI 1: bf16 out = acc + bias + fp32 residual   (Wo -> x1b)
// EPI 2: fp32 out = acc + bias + bf16 residual   (W2 -> final out)
template<int EPI>
__global__ __launch_bounds__(256, 2)
void gemm_nt(const unsigned short* __restrict__ A, const unsigned short* __restrict__ B,
             const float* __restrict__ bias, const void* __restrict__ res,
             void* __restrict__ C, int M, int N, int K)
{
    __shared__ unsigned short As[128 * 64];
    __shared__ unsigned short Bs[128 * 64];
    const int m0 = blockIdx.y * 128, n0 = blockIdx.x * 128;
    const int tid = threadIdx.x, wave = tid >> 6, lane = tid & 63;
    const int wm = (wave >> 1) * 64, wn = (wave & 1) * 64;
    const int lrow = lane & 15, quad = lane >> 4;
    const int srow = wave * 32 + (lane >> 3);
    const int scol = (((lane & 7) ^ ((lane >> 3) & 7)) << 3);
    const int ca0 = (quad ^ (lrow & 7)) << 3;
    const int ca1 = ((quad + 4) ^ (lrow & 7)) << 3;

    floatx4 acc[4][4] = {};
    const unsigned short* gA = A + (size_t)(m0 + srow) * K + scol;
    const unsigned short* gB = B + (size_t)(n0 + srow) * K + scol;
    unsigned short* lA = &As[(wave * 32) * 64];
    unsigned short* lB = &Bs[(wave * 32) * 64];

    auto stage = [&](int kk) {
#pragma unroll
        for (int r = 0; r < 4; r++) {
            async16(gA + kk + (size_t)(r * 8) * K, lA + r * 8 * 64);
            async16(gB + kk + (size_t)(r * 8) * K, lB + r * 8 * 64);
        }
    };

    stage(0);
    __syncthreads();                                  // tile 0 resident

    for (int k0 = 0; k0 < K; k0 += 64) {
        // hoist ALL fragments of tile t into registers
        short8 af[4][2], bf[4][2];
#pragma unroll
        for (int ks = 0; ks < 2; ks++) {
            const int ca = ks ? ca1 : ca0;
#pragma unroll
            for (int i = 0; i < 4; i++)
                af[i][ks] = *reinterpret_cast<const short8*>(&As[(wm + i * 16 + lrow) * 64 + ca]);
#pragma unroll
            for (int j = 0; j < 4; j++)
                bf[j][ks] = *reinterpret_cast<const short8*>(&Bs[(wn + j * 16 + lrow) * 64 + ca]);
        }
        __asm__ volatile("s_waitcnt lgkmcnt(0)" ::: "memory");  // frags landed in regs
        __builtin_amdgcn_sched_barrier(0);                      // rule #18 fence
        __builtin_amdgcn_s_barrier();                           // all waves done reading LDS

        if (k0 + 64 < K) stage(k0 + 64);                        // DMA t+1 under the MFMA cluster

        __builtin_amdgcn_s_setprio(1);
#pragma unroll
        for (int ks = 0; ks < 2; ks++)
#pragma unroll
            for (int i = 0; i < 4; i++)
#pragma unroll
                for (int j = 0; j < 4; j++)
                    acc[i][j] = __builtin_amdgcn_mfma_f32_16x16x32_bf16(af[i][ks], bf[j][ks], acc[i][j], 0, 0, 0);
        __builtin_amdgcn_s_setprio(0);

        __asm__ volatile("s_waitcnt vmcnt(0)" ::: "memory");    // t+1's DMA done (a cluster old)
        __builtin_amdgcn_s_barrier();
        __builtin_amdgcn_sched_barrier(0);
    }

#pragma unroll
    for (int i = 0; i < 4; i++) {
        int rb = m0 + wm + i * 16 + quad * 4;
#pragma unroll
        for (int j = 0; j < 4; j++) {
            int col = n0 + wn + j * 16 + lrow;
            float bv = bias[col];
#pragma unroll
            for (int r = 0; r < 4; r++) {
                size_t idx = (size_t)(rb + r) * N + col;
                float v = acc[i][j][r] + bv;
                if (EPI == 1) {
                    v += ((const float*)res)[idx];
                    ((unsigned short*)C)[idx] = f2b(v);
                } else {
                    v += b2f(((const unsigned short*)res)[idx]);
                    ((float*)C)[idx] = v;
                }
            }
        }
    }
}

// ---------------- fused QKV (BK=64 swizzled); Q pre-scaled; V -> per-head transposed Vt ------
// Vt keys PRE-PERMUTED within each 32-key window by pi^-1 so attn's PV consumes P directly
// from registers: pi(quad*8+i) = (i>>2)*16 + quad*4 + (i&3)  [A-slot -> key], bijective on [0,32).
// R10-verified form: 3-resident (1536 blocks), classic 2-barrier loop. R11 measured: trading
// occ 3->2 for the overlap schedule = +15us total. Keep occ 3.
__global__ __launch_bounds__(256, 3)
void gemm_qkv(const unsigned short* __restrict__ A, const unsigned short* __restrict__ Wqkv,
              const float* __restrict__ bq, const float* __restrict__ bk, const float* __restrict__ bv,
              unsigned short* __restrict__ QK, unsigned short* __restrict__ Vt)
{
    __shared__ unsigned short As[128 * 64];
    __shared__ unsigned short Bs[128 * 64];
    const int part = blockIdx.x >> 3;            // 0=Q 1=K 2=V
    const int m0 = blockIdx.y * 128, n0 = (blockIdx.x & 7) * 128;
    const int tid = threadIdx.x, wave = tid >> 6, lane = tid & 63;
    const int wm = (wave >> 1) * 64, wn = (wave & 1) * 64;
    const int lrow = lane & 15, quad = lane >> 4;
    const int srow = wave * 32 + (lane >> 3);
    const int scol = (((lane & 7) ^ ((lane >> 3) & 7)) << 3);
    const int ca0 = (quad ^ (lrow & 7)) << 3;
    const int ca1 = ((quad + 4) ^ (lrow & 7)) << 3;
    const unsigned short* B = Wqkv + (size_t)part * 1048576;
    const float* bias = (part == 0) ? bq : (part == 1) ? bk : bv;

    floatx4 acc[4][4] = {};
    const unsigned short* gA = A + (size_t)(m0 + srow) * 1024 + scol;
    const unsigned short* gB = B + (size_t)(n0 + srow) * 1024 + scol;
    unsigned short* lA = &As[(wave * 32) * 64];
    unsigned short* lB = &Bs[(wave * 32) * 64];

    for (int k0 = 0; k0 < 1024; k0 += 64) {
        __syncthreads();
#pragma unroll
        for (int r = 0; r < 4; r++) {
            async16(gA + k0 + (size_t)(r * 8) * 1024, lA + r * 8 * 64);
            async16(gB + k0 + (size_t)(r * 8) * 1024, lB + r * 8 * 64);
        }
        __syncthreads();
#pragma unroll
        for (int ks = 0; ks < 2; ks++) {
            const int ca = ks ? ca1 : ca0;
            short8 af[4], bf[4];
#pragma unroll
            for (int i = 0; i < 4; i++)
                af[i] = *reinterpret_cast<const short8*>(&As[(wm + i * 16 + lrow) * 64 + ca]);
#pragma unroll
            for (int j = 0; j < 4; j++)
                bf[j] = *reinterpret_cast<const short8*>(&Bs[(wn + j * 16 + lrow) * 64 + ca]);
#pragma unroll
            for (int i = 0; i < 4; i++)
#pragma unroll
                for (int j = 0; j < 4; j++)
                    acc[i][j] = __builtin_amdgcn_mfma_f32_16x16x32_bf16(af[i], bf[j], acc[i][j], 0, 0, 0);
        }
    }

#pragma unroll
    for (int i = 0; i < 4; i++) {
        int rb = m0 + wm + i * 16 + quad * 4;
#pragma unroll
        for (int j = 0; j < 4; j++) {
            int col = n0 + wn + j * 16 + lrow;
            float bv2 = bias[col];
            if (part == 0) {
#pragma unroll
                for (int r = 0; r < 4; r++)
                    QK[(size_t)(rb + r) * 1024 + col] = f2b((acc[i][j][r] + bv2) * EXP2_SCALE);
            } else if (part == 1) {
                unsigned short* dst = QK + 8388608;
#pragma unroll
                for (int r = 0; r < 4; r++)
                    dst[(size_t)(rb + r) * 1024 + col] = f2b(acc[i][j][r] + bv2);
            } else {
                int b = rb >> 11, spos = rb & 2047;
                // pi^-1 on the 32-key window: key k -> slot ((k>>2)&3)*8 + (k>>4)*4 + (k&3);
                // rb is 4-aligned so the 4 r-values stay contiguous.
                int local = spos & 31;
                int sposP = (spos & ~31) | (((local >> 2) & 3) * 8 + ((local >> 4) << 2));
                int h = col >> 6, d = col & 63;
                unsigned short* dst = Vt + (((size_t)(b * 16 + h) * 64 + d) << 11) + sposP;
                unsigned int u01 = cvtpk(acc[i][j][0] + bv2, acc[i][j][1] + bv2);
                unsigned int u23 = cvtpk(acc[i][j][2] + bv2, acc[i][j][3] + bv2);
                *reinterpret_cast<uint2*>(dst) = make_uint2(u01, u23);
            }
        }
    }
}

// ---------------- Fused W1 + ReGLU (BK=64 swizzled), overlapped single-buffer staging -------
// R9-verified: per tile: hoist all 24 frags to regs -> lgkm(0)+barrier (LDS free) -> DMA tile
// t+1 into SAME buffer -> 64-MFMA cluster overlaps DMA -> vmcnt(0) (a cluster old) + barrier.
__global__ __launch_bounds__(256, 2)
void gemm_w1_reglu(const unsigned short* __restrict__ A, const unsigned short* __restrict__ B,
                   const float* __restrict__ bias, unsigned short* __restrict__ G)
{
    __shared__ unsigned short As[128 * 64];
    __shared__ unsigned short B0s[128 * 64];
    __shared__ unsigned short B1s[128 * 64];
    const int m0 = blockIdx.y * 128, n0 = blockIdx.x * 128;  // n0 in [0,2048)
    const int tid = threadIdx.x, wave = tid >> 6, lane = tid & 63;
    const int wm = (wave >> 1) * 64, wn = (wave & 1) * 64;
    const int lrow = lane & 15, quad = lane >> 4;
    const int srow = wave * 32 + (lane >> 3);
    const int scol = (((lane & 7) ^ ((lane >> 3) & 7)) << 3);
    const int ca0 = (quad ^ (lrow & 7)) << 3;
    const int ca1 = ((quad + 4) ^ (lrow & 7)) << 3;

    floatx4 acca[4][4] = {};
    floatx4 accb[4][4] = {};
    const unsigned short* gA  = A + (size_t)(m0 + srow) * 1024 + scol;
    const unsigned short* gB0 = B + (size_t)(n0 + srow) * 1024 + scol;
    const unsigned short* gB1 = B + (size_t)(2048 + n0 + srow) * 1024 + scol;
    unsigned short* lA  = &As [(wave * 32) * 64];
    unsigned short* lB0 = &B0s[(wave * 32) * 64];
    unsigned short* lB1 = &B1s[(wave * 32) * 64];

    auto stage = [&](int kk) {
#pragma unroll
        for (int r = 0; r < 4; r++) {
            async16(gA  + kk + (size_t)(r * 8) * 1024, lA  + r * 8 * 64);
            async16(gB0 + kk + (size_t)(r * 8) * 1024, lB0 + r * 8 * 64);
            async16(gB1 + kk + (size_t)(r * 8) * 1024, lB1 + r * 8 * 64);
        }
    };

    stage(0);
    __syncthreads();                                  // tile 0 resident

    for (int k0 = 0; k0 < 1024; k0 += 64) {
        // hoist ALL fragments of tile t into registers
        short8 af[4][2], b0f[4][2], b1f[4][2];
#pragma unroll
        for (int ks = 0; ks < 2; ks++) {
            const int ca = ks ? ca1 : ca0;
#pragma unroll
            for (int i = 0; i < 4; i++)
                af[i][ks] = *reinterpret_cast<const short8*>(&As[(wm + i * 16 + lrow) * 64 + ca]);
#pragma unroll
            for (int j = 0; j < 4; j++) {
                b0f[j][ks] = *reinterpret_cast<const short8*>(&B0s[(wn + j * 16 + lrow) * 64 + ca]);
                b1f[j][ks] = *reinterpret_cast<const short8*>(&B1s[(wn + j * 16 + lrow) * 64 + ca]);
            }
        }
        __asm__ volatile("s_waitcnt lgkmcnt(0)" ::: "memory");  // frags landed in regs
        __builtin_amdgcn_sched_barrier(0);                      // rule #18 fence
        __builtin_amdgcn_s_barrier();                           // all waves done reading LDS

        if (k0 < 960) stage(k0 + 64);                           // DMA t+1 under the MFMA cluster

        __builtin_amdgcn_s_setprio(1);
#pragma unroll
        for (int ks = 0; ks < 2; ks++)
#pragma unroll
            for (int i = 0; i < 4; i++)
#pragma unroll
                for (int j = 0; j < 4; j++) {
                    acca[i][j] = __builtin_amdgcn_mfma_f32_16x16x32_bf16(af[i][ks], b0f[j][ks], acca[i][j], 0, 0, 0);
                    accb[i][j] = __builtin_amdgcn_mfma_f32_16x16x32_bf16(af[i][ks], b1f[j][ks], accb[i][j], 0, 0, 0);
                }
        __builtin_amdgcn_s_setprio(0);

        __asm__ volatile("s_waitcnt vmcnt(0)" ::: "memory");    // t+1's DMA done (a cluster old)
        __builtin_amdgcn_s_barrier();
        __builtin_amdgcn_sched_barrier(0);
    }

#pragma unroll
    for (int i = 0; i < 4; i++) {
        int rb = m0 + wm + i * 16 + quad * 4;
#pragma unroll
        for (int j = 0; j < 4; j++) {
            int col = n0 + wn + j * 16 + lrow;
            float ba = bias[col], bb2 = bias[2048 + col];
#pragma unroll
            for (int r = 0; r < 4; r++) {
                float va = acca[i][j][r] + ba;
                float vb = accb[i][j][r] + bb2;
                G[(size_t)(rb + r) * 2048 + col] = f2b(fmaxf(va, 0.0f) * vb);
            }
        }
    }
}

// ---------------- Flash attention: register-P + K/V dbuf, occupancy 4, XCD-swizzled ----------
// R8-verified (77.6 us, bank conflicts = 0): P never touches LDS (Vt pre-permuted by pi so the
// S^T C-layout registers ARE the PV A-operand after cvtpk); K/V double-buffered with counted
// vmcnt(4) + raw barriers at 4 blocks/CU; per-XCD K/V = 4MB = one L2.
__global__ __launch_bounds__(256, 4)
void attn_kernel(const unsigned short* __restrict__ Qm, const unsigned short* __restrict__ Km,
                 const unsigned short* __restrict__ Vt, unsigned short* __restrict__ ctx)
{
    __shared__ unsigned short Ks[2][64 * 64];   // [buf][key][d], chunk-swizzled
    __shared__ unsigned short Vs[2][64 * 64];   // [buf][d][key(pi-permuted)], chunk-swizzled

    const int tid = threadIdx.x, wave = tid >> 6, lane = tid & 63;
    const int lrow = lane & 15, quad = lane >> 4;
    const int id = blockIdx.x + (blockIdx.y << 4);          // grid (16,64), 1024 blocks
    const int qb = id >> 6;                                 // [0,16)
    const int bh = ((id & 7) << 3) + ((id >> 3) & 7);       // [0,64): XCD x -> heads [8x,8x+8)
    const size_t base  = (size_t)(bh >> 4) * 2048 * 1024 + (size_t)(bh & 15) * 64;
    const size_t vbase = (size_t)bh * 131072;   // Vt head base [d][2048]
    const int q0 = qb * 128 + wave * 32;
    const int g_sub = (lane >> 3);
    const int g_col = (((lane & 7) ^ (g_sub & 7)) << 3);
    const int ca0 = (quad ^ (lrow & 7)) << 3;
    const int ca1 = ((quad + 4) ^ (lrow & 7)) << 3;

    short8 qf[2][2];
#pragma unroll
    for (int m = 0; m < 2; m++) {
        const unsigned short* qp = Qm + base + (size_t)(q0 + m * 16 + lrow) * 1024 + quad * 8;
        qf[m][0] = *reinterpret_cast<const short8*>(qp);
        qf[m][1] = *reinterpret_cast<const short8*>(qp + 32);
    }
    __asm__ volatile("s_waitcnt vmcnt(0)" ::: "memory");  // Q drained: steady-state vmcnt = DMA only

    floatx4 o[2][4] = {};
    float li[2] = {0.f, 0.f};
    const floatx4 fzero = {0.f, 0.f, 0.f, 0.f};

    auto stage = [&](int buf, int k0) {
#pragma unroll
        for (int r = 0; r < 2; r++) {
            int krow = wave * 16 + r * 8 + g_sub;
            async16(Km + base + (size_t)(k0 + krow) * 1024 + g_col, &Ks[buf][(wave * 16 + r * 8) * 64]);
            async16(Vt + vbase + (size_t)krow * 2048 + k0 + g_col,  &Vs[buf][(wave * 16 + r * 8) * 64]);
        }
    };

    auto compute = [&](int buf) {
        // S^T = K Q^T (Q pre-scaled by 0.125*log2e)
        short8 kf0[4], kf1[4];
#pragma unroll
        for (int j = 0; j < 4; j++) {
            kf0[j] = *reinterpret_cast<const short8*>(&Ks[buf][(j * 16 + lrow) * 64 + ca0]);
            kf1[j] = *reinterpret_cast<const short8*>(&Ks[buf][(j * 16 + lrow) * 64 + ca1]);
        }
        floatx4 s4t[2][4];
        __builtin_amdgcn_s_setprio(1);
#pragma unroll
        for (int m = 0; m < 2; m++)
#pragma unroll
            for (int j = 0; j < 4; j++) {
                s4t[m][j] = __builtin_amdgcn_mfma_f32_16x16x32_bf16(kf0[j], qf[m][0], fzero, 0, 0, 0);
                s4t[m][j] = __builtin_amdgcn_mfma_f32_16x16x32_bf16(kf1[j], qf[m][1], s4t[m][j], 0, 0, 0);
            }
        __builtin_amdgcn_s_setprio(0);

        // p = exp2(s) packed straight into PV A-fragments (register order (j,r) == pi slot order)
        short8 pfs[2][2];
#pragma unroll
        for (int m = 0; m < 2; m++) {
            float acc = 0.f;
            unsigned int dw[8];
#pragma unroll
            for (int j = 0; j < 4; j++) {
                float p0 = __builtin_amdgcn_exp2f(s4t[m][j][0]);
                float p1 = __builtin_amdgcn_exp2f(s4t[m][j][1]);
                float p2 = __builtin_amdgcn_exp2f(s4t[m][j][2]);
                float p3 = __builtin_amdgcn_exp2f(s4t[m][j][3]);
                acc += (p0 + p1) + (p2 + p3);
                dw[2 * j]     = cvtpk(p0, p1);
                dw[2 * j + 1] = cvtpk(p2, p3);
            }
            li[m] += acc;
            pfs[m][0] = *reinterpret_cast<const short8*>(&dw[0]);
            pfs[m][1] = *reinterpret_cast<const short8*>(&dw[4]);
        }

        // O += P V (V keys pre-permuted to match)
#pragma unroll
        for (int jj = 0; jj < 4; jj++) {
            short8 vf0 = *reinterpret_cast<const short8*>(&Vs[buf][(jj * 16 + lrow) * 64 + ca0]);
            short8 vf1 = *reinterpret_cast<const short8*>(&Vs[buf][(jj * 16 + lrow) * 64 + ca1]);
            __builtin_amdgcn_s_setprio(1);
#pragma unroll
            for (int m = 0; m < 2; m++) {
                o[m][jj] = __builtin_amdgcn_mfma_f32_16x16x32_bf16(pfs[m][0], vf0, o[m][jj], 0, 0, 0);
                o[m][jj] = __builtin_amdgcn_mfma_f32_16x16x32_bf16(pfs[m][1], vf1, o[m][jj], 0, 0, 0);
            }
            __builtin_amdgcn_s_setprio(0);
        }
    };

    stage(0, 0);
    for (int t = 0; t < 31; t++) {
        stage((t + 1) & 1, (t + 1) << 6);                    // prefetch next tile into other buf
        __asm__ volatile("s_waitcnt vmcnt(4)" ::: "memory"); // tile t's 4 DMA done; t+1's in flight
        __builtin_amdgcn_s_barrier();
        __builtin_amdgcn_sched_barrier(0);                   // no LDS reads above the barrier
        compute(t & 1);
        __builtin_amdgcn_sched_barrier(0);                   // no LDS ops below the barrier
        __builtin_amdgcn_s_barrier();                        // buf(t&1) free for overwrite next iter
    }
    __asm__ volatile("s_waitcnt vmcnt(0)" ::: "memory");     // drain tile 31
    __builtin_amdgcn_s_barrier();
    __builtin_amdgcn_sched_barrier(0);
    compute(1);

    // epilogue: row-sum across quads; per-row inv via shuffle
#pragma unroll
    for (int m = 0; m < 2; m++) {
        float l = li[m];
        l += __shfl_xor(l, 16, 64);
        l += __shfl_xor(l, 32, 64);
        float inv = 1.0f / l;
#pragma unroll
        for (int r = 0; r < 4; r++) {
            float invr = __shfl(inv, quad * 4 + r, 64);
            int srow = q0 + m * 16 + quad * 4 + r;
#pragma unroll
            for (int jj = 0; jj < 4; jj++)
                ctx[base + (size_t)srow * 1024 + jj * 16 + lrow] = f2b(o[m][jj][r] * invr);
        }
    }
}

extern "C" void kernel_launch(void* const* d_in, const int* in_sizes, int n_in,
                              void* d_out, int out_size, void* d_ws, size_t ws_size,
                              hipStream_t stream) {
    const float* x    = (const float*)d_in[0];
    const float* Wq   = (const float*)d_in[1];
    const float* bq   = (const float*)d_in[2];
    const float* Wk   = (const float*)d_in[3];
    const float* bk   = (const float*)d_in[4];
    const float* Wv   = (const float*)d_in[5];
    const float* bv   = (const float*)d_in[6];
    const float* Wo   = (const float*)d_in[7];
    const float* bo   = (const float*)d_in[8];
    const float* ln1g = (const float*)d_in[9];
    const float* ln1b = (const float*)d_in[10];
    const float* ln2g = (const float*)d_in[11];
    const float* ln2b = (const float*)d_in[12];
    const float* W1   = (const float*)d_in[13];
    const float* b1   = (const float*)d_in[14];
    const float* W2   = (const float*)d_in[15];
    const float* b2   = (const float*)d_in[16];
    float* out = (float*)d_out;

    char* ws = (char*)d_ws;
    // Workspace (100 MB peak):
    // [0,20MB)   bf16 weights flat: wq wk wv wo w1 w2
    // [20,36MB)  xn -> ctx -> xn2 (bf16 8192x1024)
    // [36,52MB)  Q   -> x1b (bf16 residual after attention)
    // [52,68MB)  K
    // [68,84MB)  Vt (pi-permuted keys)  }  g (bf16 8192x2048) overlays [68,100)
    unsigned short* wflat = (unsigned short*)ws;
    unsigned short* wqb = wflat;
    unsigned short* wob = wflat + 3145728;
    unsigned short* w1b = wflat + 4194304;
    unsigned short* w2b = wflat + 8388608;
    unsigned short* xn  = (unsigned short*)(ws + 20971520);
    unsigned short* Qm  = (unsigned short*)(ws + 37748736);
    unsigned short* x1b = (unsigned short*)(ws + 37748736);
    unsigned short* Vt  = (unsigned short*)(ws + 71303168);
    unsigned short* g   = (unsigned short*)(ws + 71303168);

    dim3 blk(256);
    // fused weight-cvt + LN1
    prep_kernel<<<13312, blk, 0, stream>>>(Wq, Wk, Wv, Wo, W1, W2, wflat, x, ln1g, ln1b, xn);
    gemm_qkv<<<dim3(24, 64), blk, 0, stream>>>(xn, wqb, bq, bk, bv, Qm, Vt);
    attn_kernel<<<dim3(16, 64), blk, 0, stream>>>(Qm, Qm + 8388608, Vt, xn);
    // Wo + residual(x fp32) -> x1b (bf16, overwrites Q region)
    gemm_nt<1><<<dim3(8, 64), blk, 0, stream>>>(xn, wob, bo, x, x1b, 8192, 1024, 1024);
    ln_kernel<<<8192, blk, 0, stream>>>(x1b, ln2g, ln2b, xn);
    gemm_w1_reglu<<<dim3(16, 64), blk, 0, stream>>>(xn, w1b, b1, g);
    // W2 + residual(x1b bf16) -> out fp32
    gemm_nt<2><<<dim3(8, 64), blk, 0, stream>>>(g, w2b, b2, x1b, out, 8192, 1024, 2048);
}